// Round 13
// baseline (342.711 us; speedup 1.0000x reference)
//
#include <hip/hip_runtime.h>
#include <hip/hip_bf16.h>
#include <math.h>

// SentenceGP: B=16,S=1024,D=1024,M=1024,O=1024
// out = [mean (16,1024,1024) f32][softplus(var) (16,1024,1024) f32]
//
// Pipeline (R13 = R11 dispatch structure + var written by fat3's q-ticket):
//  prep_ipw: ip->bf16 + norms | W->bf16 | rs=0
//  fat1: kii(64, first) || prep_x(2048)            [kii hidden]
//  gmax: c = 1/max_rowsum, s = sqrt(c)
//  fat2: batch1{R2,T1}(128, first) || Kxi(1024)    [batch1 hidden; zeroes qb+tick]
//  batch2a: S -> U[0:1024]                         [64 blocks, exposed]
//  fat3: batch2b{W2T}(64, first) || q(1024); last col-block per row-panel
//        writes var = softplus(1-q) via ticket     [W2T + var hidden]
//  kmean: mean = Kxi@W2T^T -> d_out (mean only, no q dependency)
//
// Big-GEMM body: 128x128 tile, BK=64, 4 waves, 64 KiB LDS, 2 blocks/CU,
// XOR-swizzled LDS, counted vmcnt(4)/tile, one s_barrier/phase.

typedef unsigned short u16;
typedef __attribute__((ext_vector_type(8))) short short8;
typedef __attribute__((ext_vector_type(4))) float f32x4;
typedef __attribute__((ext_vector_type(4))) unsigned short us4;

__device__ __forceinline__ float bf2f(u16 b) {
  union { unsigned u; float f; } x; x.u = ((unsigned)b) << 16; return x.f;
}
__device__ __forceinline__ u16 f2bf(float f) {
  union { float f; unsigned u; } x; x.f = f;
  unsigned r = x.u + 0x7fffu + ((x.u >> 16) & 1u);
  return (u16)(r >> 16);
}

__device__ __forceinline__ void gl_lds16(const void* g, void* l) {
  __builtin_amdgcn_global_load_lds(
      (const __attribute__((address_space(1))) void*)g,
      (__attribute__((address_space(3))) void*)l, 16, 0, 0);
}

// =================== big GEMM body: 128^2, 4 waves, 2 blocks/CU ============
// EPI 0: Kxi = bf16(exp(-inv2*max(rn+cn-2c,0))); zeroes qb + tick.
// EPI 1: mean f32 store only.
// EPI 2: q[row] += sum_col acc^2 (atomic); LAST col-block of each row-panel
//        (ticket) computes softplus(1-q) and writes the var rows. All 8
//        col-blocks of a panel share one XCD (swizzle) -> local-L2 atomics.
template <int EPI>
__device__ __forceinline__ void big_body(
    int bid, u16* lds,
    const u16* Ag, const u16* Bg,
    float* outF, float* varF, u16* outB,
    const float* rowN, const float* colN,
    const float* p_ll, float* qb, unsigned* tick) {
  constexpr int NT = 16;  // K / 64
  const int tid = threadIdx.x;
  const int lane = tid & 63;
  const int wave = tid >> 6;                  // 4 waves
  const int wr = wave >> 1, wc = wave & 1;    // 2 x 2
  const int fro = lane & 15, khi = lane >> 4;
  const int xcd = bid & 7, j7 = bid >> 3;
  const size_t brow = (size_t)(xcd * 16 + (j7 >> 3));  // row-panel -> one XCD
  const size_t bcol = (size_t)(j7 & 7);

  if (EPI == 0) {  // zero q accumulator + tickets for the later q pass
    if (tid < 16) qb[(size_t)bid * 16 + tid] = 0.0f;
    if (tid == 16 && bid < 128) tick[bid] = 0u;
  }

  f32x4 acc[4][4] = {};

  auto stageA = [&](int tt, int bb) {
#pragma unroll
    for (int c = 0; c < 4; ++c) {
      const int ci = tid + 256 * c;      // 1024 chunks of 8 u16
      const int row = ci >> 3;           // 0..127
      const int gk = (ci & 7) ^ (row & 7);
      gl_lds16(Ag + (size_t)(brow * 128 + row) * 1024 + tt * 64 + gk * 8,
               &lds[bb * 16384 + ci * 8]);
    }
  };
  auto stageB = [&](int tt, int bb) {
#pragma unroll
    for (int c = 0; c < 4; ++c) {
      const int ci = tid + 256 * c;
      const int row = ci >> 3;
      const int gk = (ci & 7) ^ (row & 7);
      gl_lds16(Bg + (size_t)(bcol * 128 + row) * 1024 + tt * 64 + gk * 8,
               &lds[bb * 16384 + 8192 + ci * 8]);
    }
  };

  // prologue: A(0)+B(0) -> buf0, B(1) -> buf1. vmcnt(4): tile0 landed.
  stageA(0, 0);
  stageB(0, 0);
  stageB(1, 1);
  asm volatile("s_waitcnt vmcnt(4)" ::: "memory");
  __builtin_amdgcn_s_barrier();

  for (int t = 0; t < NT; ++t) {
    const int cb = t & 1;
    const int ab = cb * 16384;
    const int bb = cb * 16384 + 8192;
    short8 bfrag[4][2];
#pragma unroll
    for (int p = 0; p < 4; ++p) {
      short8 afr[2];
      const int rr = wr * 64 + p * 16 + fro;
#pragma unroll
      for (int s = 0; s < 2; ++s) {
        const int kl = (s * 4 + khi) ^ (rr & 7);
        afr[s] = *(const short8*)&lds[ab + (rr * 8 + kl) * 8];
      }
      if (p == 0) {
#pragma unroll
        for (int n = 0; n < 4; ++n) {
          const int cc = wc * 64 + n * 16 + fro;
#pragma unroll
          for (int s = 0; s < 2; ++s) {
            const int kl = (s * 4 + khi) ^ (cc & 7);
            bfrag[n][s] = *(const short8*)&lds[bb + (cc * 8 + kl) * 8];
          }
        }
        if (t + 1 < NT) stageA(t + 1, cb ^ 1);   // A(t-1) done @ t-1 p3
      } else if (p == 1) {
        if (t + 2 < NT) stageB(t + 2, cb);        // B(t) done @ p0
      }
      __builtin_amdgcn_s_setprio(1);
#pragma unroll
      for (int n = 0; n < 4; ++n)
#pragma unroll
        for (int s = 0; s < 2; ++s)
          acc[p][n] = __builtin_amdgcn_mfma_f32_16x16x32_bf16(
              afr[s], bfrag[n][s], acc[p][n], 0, 0, 0);
      __builtin_amdgcn_s_setprio(0);
      if (p == 3) {
        if (t < NT - 2) asm volatile("s_waitcnt vmcnt(4)" ::: "memory");
        else            asm volatile("s_waitcnt vmcnt(0)" ::: "memory");
      }
      __builtin_amdgcn_s_barrier();
    }
  }

  // ---- epilogue ----
  float inv2 = 0.f;
  if (EPI == 0) inv2 = 0.5f * expf(-2.0f * p_ll[0]);
#pragma unroll
  for (int m = 0; m < 4; m++) {
#pragma unroll
    for (int j = 0; j < 4; j++) {
      const size_t grow = brow * 128 + wr * 64 + m * 16 + khi * 4 + j;
      float rn = 0.f;
      if (EPI == 0) rn = rowN[grow];
      float part = 0.f;
#pragma unroll
      for (int n = 0; n < 4; n++) {
        const size_t gcol = bcol * 128 + wc * 64 + n * 16 + fro;
        const size_t o = grow * 1024 + gcol;
        float v = acc[m][n][j];
        if (EPI == 0) {
          float d2 = fmaxf(rn + colN[gcol] - 2.0f * v, 0.0f);
          outB[o] = f2bf(expf(-inv2 * d2));
        } else if (EPI == 1) {
          outF[o] = v;
        } else {
          part += v * v;
        }
      }
      if (EPI == 2) {
        part += __shfl_xor(part, 1);
        part += __shfl_xor(part, 2);
        part += __shfl_xor(part, 4);
        part += __shfl_xor(part, 8);
        if (fro == 0) atomicAdd(&qb[grow], part);
      }
    }
  }

  // ---- EPI 2: ticket; last col-block of this row-panel writes var ----
  if (EPI == 2) {
    __syncthreads();        // all q atomicAdds of this block issued
    __threadfence();        // make them globally visible before the ticket
    volatile unsigned* lastp = (volatile unsigned*)lds;  // K-loop LDS is dead
    if (tid == 0) lastp[0] = (atomicAdd(&tick[brow], 1u) == 7u) ? 1u : 0u;
    __syncthreads();
    if (lastp[0]) {
      __threadfence();      // acquire side: other blocks' adds visible
      for (int r = wave; r < 128; r += 4) {
        float qv = __hip_atomic_load(&qb[brow * 128 + r], __ATOMIC_RELAXED,
                                     __HIP_MEMORY_SCOPE_AGENT);
        float vq = 1.0f - qv;  // K_xx diag == 1 exactly
        float sp = fmaxf(vq, 0.f) + log1pf(expf(-fabsf(vq)));
        float4 o4 = {sp, sp, sp, sp};
        float4* dst = (float4*)(varF + (size_t)(brow * 128 + r) * 1024);
#pragma unroll
        for (int cc = lane; cc < 256; cc += 64) dst[cc] = o4;
      }
    }
  }
}

// =================== small 128^2 GEMM core (K=1024, B^T layout) ===========
__device__ __forceinline__ void small_core(const u16* Ap, const u16* Bp,
                                           u16* As, u16* Bs,
                                           f32x4 (&acc)[4][4]) {
  const int tid = threadIdx.x;
  const int lane = tid & 63;
  const int wave = tid >> 6;
  const int wr = wave >> 1, wc = wave & 1;
  const int idx0 = tid, idx1 = tid + 256;
  const u16* gA0 = Ap + (size_t)(idx0 >> 2) * 1024 + (size_t)(idx0 & 3) * 8;
  const u16* gA1 = Ap + (size_t)(idx1 >> 2) * 1024 + (size_t)(idx1 & 3) * 8;
  const u16* gB0 = Bp + (size_t)(idx0 >> 2) * 1024 + (size_t)(idx0 & 3) * 8;
  const u16* gB1 = Bp + (size_t)(idx1 >> 2) * 1024 + (size_t)(idx1 & 3) * 8;
  u16* lA0 = &As[idx0 * 8]; u16* lA1 = &As[idx1 * 8];
  u16* lB0 = &Bs[idx0 * 8]; u16* lB1 = &Bs[idx1 * 8];
  const int fro = lane & 15;
  const int ko = (lane >> 4) * 8;

  for (int kt = 0; kt < 1024; kt += 32) {
    gl_lds16(gA0 + kt, lA0);
    gl_lds16(gA1 + kt, lA1);
    gl_lds16(gB0 + kt, lB0);
    gl_lds16(gB1 + kt, lB1);
    __syncthreads();
    short8 af[4], bfr[4];
#pragma unroll
    for (int m = 0; m < 4; m++) {
      af[m]  = *(const short8*)&As[(wr * 64 + m * 16 + fro) * 32 + ko];
      bfr[m] = *(const short8*)&Bs[(wc * 64 + m * 16 + fro) * 32 + ko];
    }
#pragma unroll
    for (int m = 0; m < 4; m++)
#pragma unroll
      for (int n = 0; n < 4; n++)
        acc[m][n] = __builtin_amdgcn_mfma_f32_16x16x32_bf16(af[m], bfr[n], acc[m][n], 0, 0, 0);
    __syncthreads();
  }
}

// ---------- kii body: rbf(ip,ip), diag=1+noise, fused Gershgorin ----------
__device__ __forceinline__ void kii_body(int bid, u16* lds,
                                         const u16* ipb, u16* kii,
                                         const float* ni, const float* ll,
                                         const float* ln, float* rs) {
  const int by = bid >> 3, bx = bid & 7;
  f32x4 acc[4][4] = {};
  small_core(ipb + (size_t)by * 131072, ipb + (size_t)bx * 131072,
             lds, lds + 4096, acc);
  const int lane = threadIdx.x & 63;
  const int wave = threadIdx.x >> 6;
  const int wr = wave >> 1, wc = wave & 1;
  float inv2 = 0.5f * expf(-2.0f * ll[0]);
  float noise = expf(ln[0]);
#pragma unroll
  for (int m = 0; m < 4; m++)
#pragma unroll
    for (int j = 0; j < 4; j++) {
      const size_t grow = by * 128 + wr * 64 + m * 16 + (lane >> 4) * 4 + j;
      float rn = ni[grow];
      float part = 0.f;
#pragma unroll
      for (int n = 0; n < 4; n++) {
        const size_t gcol = bx * 128 + wc * 64 + n * 16 + (lane & 15);
        float d2 = fmaxf(rn + ni[gcol] - 2.0f * acc[m][n][j], 0.0f);
        float kv = (grow == gcol) ? (1.0f + noise) : expf(-inv2 * d2);
        kii[grow * 1024 + gcol] = f2bf(kv);
        part += fabsf(kv);
      }
      part += __shfl_xor(part, 1);
      part += __shfl_xor(part, 2);
      part += __shfl_xor(part, 4);
      part += __shfl_xor(part, 8);
      if ((lane & 15) == 0) atomicAdd(&rs[grow], part);
    }
}

// ---------- batch1 body: z=0: R2 = I-2cK+c^2*K@K ; z=1: T1 = 2W - c*W@K ----
__device__ __forceinline__ void batch1_body(int bid, u16* lds,
                                            const u16* kii, const u16* Wb,
                                            u16* R2b, u16* T1b,
                                            const float* sc) {
  const int z = bid >> 6, r = bid & 63;
  const int by = r >> 3, bx = r & 7;
  f32x4 acc[4][4] = {};
  const u16* Abase = z ? Wb : kii;
  small_core(Abase + (size_t)by * 131072, kii + (size_t)bx * 131072,
             lds, lds + 4096, acc);
  const int lane = threadIdx.x & 63;
  const int wave = threadIdx.x >> 6;
  const int wr = wave >> 1, wc = wave & 1;
  const float c = sc[0];
#pragma unroll
  for (int m = 0; m < 4; m++)
#pragma unroll
    for (int j = 0; j < 4; j++) {
      const size_t grow = by * 128 + wr * 64 + m * 16 + (lane >> 4) * 4 + j;
#pragma unroll
      for (int n = 0; n < 4; n++) {
        const size_t gcol = bx * 128 + wc * 64 + n * 16 + (lane & 15);
        const size_t o = grow * 1024 + gcol;
        float v = acc[m][n][j];
        if (z == 0) {
          float idv = (grow == gcol) ? 1.0f : 0.0f;
          R2b[o] = f2bf(idv - 2.0f * c * bf2f(kii[o]) + c * c * v);
        } else {
          T1b[o] = f2bf(2.0f * bf2f(Wb[o]) - c * v);
        }
      }
    }
}

// ---------- batch2 body: z=0: S -> U[0:1024] ; z=1: W2T -> U[1024:2048] ----
__device__ __forceinline__ void batch2_body(int z, int by, int bx, u16* lds,
                                            const u16* kii, const u16* R2b,
                                            const u16* T1b, u16* U,
                                            const float* sc) {
  f32x4 acc[4][4] = {};
  const u16* Abase = z ? T1b : kii;
  small_core(Abase + (size_t)by * 131072, R2b + (size_t)bx * 131072,
             lds, lds + 4096, acc);
  const int lane = threadIdx.x & 63;
  const int wave = threadIdx.x >> 6;
  const int wr = wave >> 1, wc = wave & 1;
  const float c = sc[0], s = sc[1];
#pragma unroll
  for (int m = 0; m < 4; m++)
#pragma unroll
    for (int j = 0; j < 4; j++) {
      const size_t grow = by * 128 + wr * 64 + m * 16 + (lane >> 4) * 4 + j;
#pragma unroll
      for (int n = 0; n < 4; n++) {
        const size_t gcol = bx * 128 + wc * 64 + n * 16 + (lane & 15);
        const size_t o = grow * 1024 + gcol;
        float v = acc[m][n][j];
        if (z == 0) {
          float idv = (grow == gcol) ? 1.0f : 0.0f;
          U[o] = f2bf(s * (1.5f * idv - 0.5f * c * bf2f(kii[o]) +
                           0.6875f * bf2f(R2b[o]) - 0.3125f * c * v));
        } else {
          U[o + 1048576] = f2bf(c * (bf2f(T1b[o]) + v));
        }
      }
    }
}

// ---------- prep_x body: x rows -> bf16 + row norms (stride 2048) ----------
__device__ __forceinline__ void prepx_body(int bid, u16* lds,
                                           const float* x, u16* xbf,
                                           float* nx) {
  float* wsum = (float*)lds;
  for (int r = bid; r < 16384; r += 2048) {
    const float4 v = ((const float4*)(x + (size_t)r * 1024))[threadIdx.x];
    float ss = v.x * v.x + v.y * v.y + v.z * v.z + v.w * v.w;
    us4 o; o.x = f2bf(v.x); o.y = f2bf(v.y); o.z = f2bf(v.z); o.w = f2bf(v.w);
    ((us4*)(xbf + (size_t)r * 1024))[threadIdx.x] = o;
#pragma unroll
    for (int s = 32; s > 0; s >>= 1) ss += __shfl_xor(ss, s);
    if ((threadIdx.x & 63) == 0) wsum[threadIdx.x >> 6] = ss;
    __syncthreads();
    if (threadIdx.x == 0) nx[r] = wsum[0] + wsum[1] + wsum[2] + wsum[3];
    __syncthreads();
  }
}

// =================== fat kernels ===================
// fat1: kii(64, first) || prep_x(2048)
__global__ __launch_bounds__(256) void fat1(
    const float* __restrict__ x, u16* __restrict__ xbf, float* __restrict__ nx,
    const u16* __restrict__ ipb, u16* __restrict__ kii,
    const float* __restrict__ ni, const float* __restrict__ ll,
    const float* __restrict__ ln, float* __restrict__ rs) {
  __shared__ u16 lds[8192];  // 16 KiB
  const int bid = blockIdx.x;
  if (bid < 64) kii_body(bid, lds, ipb, kii, ni, ll, ln, rs);
  else          prepx_body(bid - 64, lds, x, xbf, nx);
}

// fat2: batch1(128, first) || Kxi(1024); zeroes qb + tick
__global__ __launch_bounds__(256, 2) void fat2(
    const u16* __restrict__ xbf, const u16* __restrict__ ipb,
    u16* __restrict__ kxib,
    const float* __restrict__ nx, const float* __restrict__ ni,
    const float* __restrict__ ll, float* __restrict__ qb,
    unsigned* __restrict__ tick,
    const u16* __restrict__ kii, const u16* __restrict__ wbf,
    u16* __restrict__ R2b, u16* __restrict__ t1b,
    const float* __restrict__ sc) {
  __shared__ u16 lds[32768];  // 64 KiB
  const int bid = blockIdx.x;
  if (bid < 128) batch1_body(bid, lds, kii, wbf, R2b, t1b, sc);
  else big_body<0>(bid - 128, lds, xbf, ipb, nullptr, nullptr, kxib,
                   nx, ni, ll, qb, tick);
}

// batch2a: S only (z=0)
__global__ __launch_bounds__(256) void kbatch2a(
    const u16* __restrict__ kii, const u16* __restrict__ R2b,
    const u16* __restrict__ t1b, u16* __restrict__ U,
    const float* __restrict__ sc) {
  __shared__ u16 lds[8192];
  batch2_body(0, blockIdx.y, blockIdx.x, lds, kii, R2b, t1b, U, sc);
}

// fat3: batch2b{W2T}(64, first) || q(1024, writes var via ticket)
__global__ __launch_bounds__(256, 2) void fat3(
    const u16* __restrict__ kxib, const u16* __restrict__ U,
    float* __restrict__ varO,
    float* __restrict__ qb, unsigned* __restrict__ tick,
    const u16* __restrict__ kii, const u16* __restrict__ R2b,
    const u16* __restrict__ t1b, u16* __restrict__ Uw,
    const float* __restrict__ sc) {
  __shared__ u16 lds[32768];
  const int bid = blockIdx.x;
  if (bid < 64) batch2_body(1, bid >> 3, bid & 7, lds, kii, R2b, t1b, Uw, sc);
  else big_body<2>(bid - 64, lds, kxib, U, nullptr, varO, nullptr,
                   nullptr, nullptr, nullptr, qb, tick);
}

// mean pass (mean only; var already written by fat3)
__global__ __launch_bounds__(256, 2) void kmean(
    const u16* __restrict__ kxib, const u16* __restrict__ w2t,
    float* __restrict__ meanO) {
  __shared__ u16 lds[32768];
  big_body<1>(blockIdx.x, lds, kxib, w2t, meanO, nullptr, nullptr,
              nullptr, nullptr, nullptr, nullptr, nullptr);
}

// ---------- ip rows (norms) + W convert + rs zero ----------
__global__ __launch_bounds__(256) void prep_ipw(const float* __restrict__ ip,
                                                const float* __restrict__ W,
                                                u16* __restrict__ ipb,
                                                u16* __restrict__ wbf,
                                                float* __restrict__ ni,
                                                float* __restrict__ rs) {
  __shared__ float wsum[4];
  int b = blockIdx.x;
  if (b < 1024) {
    const float4 v = ((const float4*)(ip + (size_t)b * 1024))[threadIdx.x];
    float ss = v.x * v.x + v.y * v.y + v.z * v.z + v.w * v.w;
    us4 o; o.x = f2bf(v.x); o.y = f2bf(v.y); o.z = f2bf(v.z); o.w = f2bf(v.w);
    ((us4*)(ipb + (size_t)b * 1024))[threadIdx.x] = o;
#pragma unroll
    for (int s = 32; s > 0; s >>= 1) ss += __shfl_xor(ss, s);
    if ((threadIdx.x & 63) == 0) wsum[threadIdx.x >> 6] = ss;
    __syncthreads();
    if (threadIdx.x == 0) {
      ni[b] = wsum[0] + wsum[1] + wsum[2] + wsum[3];
      rs[b] = 0.0f;
    }
  } else {
    int r = b - 1024;
    const float4 v = ((const float4*)(W + (size_t)r * 1024))[threadIdx.x];
    us4 o; o.x = f2bf(v.x); o.y = f2bf(v.y); o.z = f2bf(v.z); o.w = f2bf(v.w);
    ((us4*)(wbf + (size_t)r * 1024))[threadIdx.x] = o;
  }
}

__global__ __launch_bounds__(256) void gmax_inv(const float* __restrict__ rs,
                                                float* __restrict__ sc) {
  __shared__ float wm[4];
  float m = 0.f;
  for (int i = threadIdx.x; i < 1024; i += 256) m = fmaxf(m, rs[i]);
#pragma unroll
  for (int o = 32; o > 0; o >>= 1) m = fmaxf(m, __shfl_xor(m, o));
  if ((threadIdx.x & 63) == 0) wm[threadIdx.x >> 6] = m;
  __syncthreads();
  if (threadIdx.x == 0) {
    float c = 1.0f / fmaxf(fmaxf(wm[0], wm[1]), fmaxf(wm[2], wm[3]));
    sc[0] = c;
    sc[1] = sqrtf(c);
  }
}

extern "C" void kernel_launch(void* const* d_in, const int* in_sizes, int n_in,
                              void* d_out, int out_size, void* d_ws, size_t ws_size,
                              hipStream_t stream) {
  const float* x  = (const float*)d_in[0];
  const float* ip = (const float*)d_in[1];
  const float* ll = (const float*)d_in[2];
  const float* ln = (const float*)d_in[3];
  const float* W  = (const float*)d_in[4];

  char* ws = (char*)d_ws;
  const size_t MB = 1ull << 20;
  u16* kxib = (u16*)(ws + 0 * MB);    // 32 MiB
  u16* xbf  = (u16*)(ws + 32 * MB);   // 32 MiB
  u16* ipb  = (u16*)(ws + 64 * MB);   // 2 MiB
  u16* wbf  = (u16*)(ws + 66 * MB);   // 2 MiB
  u16* kii  = (u16*)(ws + 68 * MB);   // 2 MiB
  u16* R2b  = (u16*)(ws + 70 * MB);   // 2 MiB
  u16* Ub   = (u16*)(ws + 74 * MB);   // 4 MiB  [S ; W2T]
  u16* t1b  = (u16*)(ws + 78 * MB);   // 2 MiB
  float* nx = (float*)(ws + 80 * MB);
  float* qb = (float*)(ws + 80 * MB + 128 * 1024);
  float* ni = (float*)(ws + 80 * MB + 256 * 1024);
  float* rs = (float*)(ws + 80 * MB + 512 * 1024);
  float* sc = (float*)(ws + 80 * MB + 768 * 1024);
  unsigned* tick = (unsigned*)(ws + 80 * MB + 1024 * 1024);

  float* meanO = (float*)d_out;
  float* varO  = meanO + 16777216ull;

  // ip/W prep (kii's inputs) first
  prep_ipw<<<2048, 256, 0, stream>>>(ip, W, ipb, wbf, ni, rs);

  // kii (64, first) || prep_x (2048)
  fat1<<<2112, 256, 0, stream>>>(x, xbf, nx, ipb, kii, ni, ll, ln, rs);

  gmax_inv<<<1, 256, 0, stream>>>(rs, sc);

  // batch1 (128, first) || Kxi (1024); qb + tick zeroed by Kxi blocks
  fat2<<<1152, 256, 0, stream>>>(xbf, ipb, kxib, nx, ni, ll, qb, tick,
                                 kii, wbf, R2b, t1b, sc);

  // S -> U[0:1024]
  kbatch2a<<<dim3(8, 8), 256, 0, stream>>>(kii, R2b, t1b, Ub, sc);

  // batch2b{W2T} (64, first) || q (1024; last block per panel writes var)
  fat3<<<1088, 256, 0, stream>>>(kxib, Ub, varO, qb, tick,
                                 kii, R2b, t1b, Ub, sc);

  // mean only -> d_out
  kmean<<<1024, 256, 0, stream>>>(kxib, Ub + 1048576, meanO);
}

// Round 14
// 212.503 us; speedup vs baseline: 1.6127x; 1.6127x over previous
//
#include <hip/hip_runtime.h>
#include <hip/hip_bf16.h>
#include <math.h>

// SentenceGP: B=16,S=1024,D=1024,M=1024,O=1024
// out = [mean (16,1024,1024) f32][softplus(var) (16,1024,1024) f32]
//
// Pipeline (R14 = R11 verbatim; R12/R13's ticket+threadfence var-write path
// was a ~150us/dispatch device-fence tax — reverted):
//  prep_ipw: ip->bf16 + norms | W->bf16 | rs=0
//  fat1: kii(64 blocks, first) || prep_x(2048)      [kii hidden]
//  gmax: c = 1/max_rowsum, s = sqrt(c)
//  fat2: batch1{R2,T1}(128, first) || Kxi(1024)     [batch1 hidden]
//  batch2a: S -> U[0:1024]                          [64 blocks, exposed]
//  fat3: batch2b{W2T}(64, first) || q(1024)         [W2T hidden]
//  mean = Kxi@W2T^T + fused var -> d_out            [qb fenced by dispatch]
//
// Big-GEMM body: 128x128 tile, BK=64, 4 waves, 64 KiB LDS, 2 blocks/CU,
// XOR-swizzled LDS, counted vmcnt(4)/tile, one s_barrier/phase (R10).

typedef unsigned short u16;
typedef __attribute__((ext_vector_type(8))) short short8;
typedef __attribute__((ext_vector_type(4))) float f32x4;
typedef __attribute__((ext_vector_type(4))) unsigned short us4;

__device__ __forceinline__ float bf2f(u16 b) {
  union { unsigned u; float f; } x; x.u = ((unsigned)b) << 16; return x.f;
}
__device__ __forceinline__ u16 f2bf(float f) {
  union { float f; unsigned u; } x; x.f = f;
  unsigned r = x.u + 0x7fffu + ((x.u >> 16) & 1u);
  return (u16)(r >> 16);
}

__device__ __forceinline__ void gl_lds16(const void* g, void* l) {
  __builtin_amdgcn_global_load_lds(
      (const __attribute__((address_space(1))) void*)g,
      (__attribute__((address_space(3))) void*)l, 16, 0, 0);
}

// =================== big GEMM body: 128^2, 4 waves, 2 blocks/CU ============
// EPI 0: Kxi = bf16(exp(-inv2*max(rn+cn-2c,0))); zeroes qb.
// EPI 1: mean f32 store + fused var = softplus(1-q[row]).
// EPI 2: q[row] += sum_col acc^2 (atomic).
template <int EPI>
__device__ __forceinline__ void big_body(
    int bid, u16* lds,
    const u16* Ag, const u16* Bg,
    float* outF, float* varF, u16* outB,
    const float* rowN, const float* colN,
    const float* p_ll, float* qb) {
  constexpr int NT = 16;  // K / 64
  const int tid = threadIdx.x;
  const int lane = tid & 63;
  const int wave = tid >> 6;                  // 4 waves
  const int wr = wave >> 1, wc = wave & 1;    // 2 x 2
  const int fro = lane & 15, khi = lane >> 4;
  const int xcd = bid & 7, j7 = bid >> 3;
  const size_t brow = (size_t)(xcd * 16 + (j7 >> 3));  // row-panel -> one XCD
  const size_t bcol = (size_t)(j7 & 7);

  if (EPI == 0) {  // zero q accumulator for the later q pass
    if (tid < 16) qb[(size_t)bid * 16 + tid] = 0.0f;
  }

  f32x4 acc[4][4] = {};

  auto stageA = [&](int tt, int bb) {
#pragma unroll
    for (int c = 0; c < 4; ++c) {
      const int ci = tid + 256 * c;      // 1024 chunks of 8 u16
      const int row = ci >> 3;           // 0..127
      const int gk = (ci & 7) ^ (row & 7);
      gl_lds16(Ag + (size_t)(brow * 128 + row) * 1024 + tt * 64 + gk * 8,
               &lds[bb * 16384 + ci * 8]);
    }
  };
  auto stageB = [&](int tt, int bb) {
#pragma unroll
    for (int c = 0; c < 4; ++c) {
      const int ci = tid + 256 * c;
      const int row = ci >> 3;
      const int gk = (ci & 7) ^ (row & 7);
      gl_lds16(Bg + (size_t)(bcol * 128 + row) * 1024 + tt * 64 + gk * 8,
               &lds[bb * 16384 + 8192 + ci * 8]);
    }
  };

  // prologue: A(0)+B(0) -> buf0, B(1) -> buf1. vmcnt(4): tile0 landed.
  stageA(0, 0);
  stageB(0, 0);
  stageB(1, 1);
  asm volatile("s_waitcnt vmcnt(4)" ::: "memory");
  __builtin_amdgcn_s_barrier();

  for (int t = 0; t < NT; ++t) {
    const int cb = t & 1;
    const int ab = cb * 16384;
    const int bb = cb * 16384 + 8192;
    short8 bfrag[4][2];
#pragma unroll
    for (int p = 0; p < 4; ++p) {
      short8 afr[2];
      const int rr = wr * 64 + p * 16 + fro;
#pragma unroll
      for (int s = 0; s < 2; ++s) {
        const int kl = (s * 4 + khi) ^ (rr & 7);
        afr[s] = *(const short8*)&lds[ab + (rr * 8 + kl) * 8];
      }
      if (p == 0) {
#pragma unroll
        for (int n = 0; n < 4; ++n) {
          const int cc = wc * 64 + n * 16 + fro;
#pragma unroll
          for (int s = 0; s < 2; ++s) {
            const int kl = (s * 4 + khi) ^ (cc & 7);
            bfrag[n][s] = *(const short8*)&lds[bb + (cc * 8 + kl) * 8];
          }
        }
        if (t + 1 < NT) stageA(t + 1, cb ^ 1);   // A(t-1) done @ t-1 p3
      } else if (p == 1) {
        if (t + 2 < NT) stageB(t + 2, cb);        // B(t) done @ p0
      }
      __builtin_amdgcn_s_setprio(1);
#pragma unroll
      for (int n = 0; n < 4; ++n)
#pragma unroll
        for (int s = 0; s < 2; ++s)
          acc[p][n] = __builtin_amdgcn_mfma_f32_16x16x32_bf16(
              afr[s], bfrag[n][s], acc[p][n], 0, 0, 0);
      __builtin_amdgcn_s_setprio(0);
      if (p == 3) {
        if (t < NT - 2) asm volatile("s_waitcnt vmcnt(4)" ::: "memory");
        else            asm volatile("s_waitcnt vmcnt(0)" ::: "memory");
      }
      __builtin_amdgcn_s_barrier();
    }
  }

  // ---- epilogue ----
  float inv2 = 0.f;
  if (EPI == 0) inv2 = 0.5f * expf(-2.0f * p_ll[0]);
#pragma unroll
  for (int m = 0; m < 4; m++) {
#pragma unroll
    for (int j = 0; j < 4; j++) {
      const size_t grow = brow * 128 + wr * 64 + m * 16 + khi * 4 + j;
      float rn = 0.f, sp = 0.f;
      if (EPI == 0) rn = rowN[grow];
      if (EPI == 1) {
        float vq = 1.0f - qb[grow];  // K_xx diag == 1 exactly
        sp = fmaxf(vq, 0.f) + log1pf(expf(-fabsf(vq)));
      }
      float part = 0.f;
#pragma unroll
      for (int n = 0; n < 4; n++) {
        const size_t gcol = bcol * 128 + wc * 64 + n * 16 + fro;
        const size_t o = grow * 1024 + gcol;
        float v = acc[m][n][j];
        if (EPI == 0) {
          float d2 = fmaxf(rn + colN[gcol] - 2.0f * v, 0.0f);
          outB[o] = f2bf(expf(-inv2 * d2));
        } else if (EPI == 1) {
          outF[o] = v;
          varF[o] = sp;
        } else {
          part += v * v;
        }
      }
      if (EPI == 2) {
        part += __shfl_xor(part, 1);
        part += __shfl_xor(part, 2);
        part += __shfl_xor(part, 4);
        part += __shfl_xor(part, 8);
        if (fro == 0) atomicAdd(&qb[grow], part);
      }
    }
  }
}

// =================== small 128^2 GEMM core (K=1024, B^T layout) ===========
__device__ __forceinline__ void small_core(const u16* Ap, const u16* Bp,
                                           u16* As, u16* Bs,
                                           f32x4 (&acc)[4][4]) {
  const int tid = threadIdx.x;
  const int lane = tid & 63;
  const int wave = tid >> 6;
  const int wr = wave >> 1, wc = wave & 1;
  const int idx0 = tid, idx1 = tid + 256;
  const u16* gA0 = Ap + (size_t)(idx0 >> 2) * 1024 + (size_t)(idx0 & 3) * 8;
  const u16* gA1 = Ap + (size_t)(idx1 >> 2) * 1024 + (size_t)(idx1 & 3) * 8;
  const u16* gB0 = Bp + (size_t)(idx0 >> 2) * 1024 + (size_t)(idx0 & 3) * 8;
  const u16* gB1 = Bp + (size_t)(idx1 >> 2) * 1024 + (size_t)(idx1 & 3) * 8;
  u16* lA0 = &As[idx0 * 8]; u16* lA1 = &As[idx1 * 8];
  u16* lB0 = &Bs[idx0 * 8]; u16* lB1 = &Bs[idx1 * 8];
  const int fro = lane & 15;
  const int ko = (lane >> 4) * 8;

  for (int kt = 0; kt < 1024; kt += 32) {
    gl_lds16(gA0 + kt, lA0);
    gl_lds16(gA1 + kt, lA1);
    gl_lds16(gB0 + kt, lB0);
    gl_lds16(gB1 + kt, lB1);
    __syncthreads();
    short8 af[4], bfr[4];
#pragma unroll
    for (int m = 0; m < 4; m++) {
      af[m]  = *(const short8*)&As[(wr * 64 + m * 16 + fro) * 32 + ko];
      bfr[m] = *(const short8*)&Bs[(wc * 64 + m * 16 + fro) * 32 + ko];
    }
#pragma unroll
    for (int m = 0; m < 4; m++)
#pragma unroll
      for (int n = 0; n < 4; n++)
        acc[m][n] = __builtin_amdgcn_mfma_f32_16x16x32_bf16(af[m], bfr[n], acc[m][n], 0, 0, 0);
    __syncthreads();
  }
}

// ---------- kii body: rbf(ip,ip), diag=1+noise, fused Gershgorin ----------
__device__ __forceinline__ void kii_body(int bid, u16* lds,
                                         const u16* ipb, u16* kii,
                                         const float* ni, const float* ll,
                                         const float* ln, float* rs) {
  const int by = bid >> 3, bx = bid & 7;
  f32x4 acc[4][4] = {};
  small_core(ipb + (size_t)by * 131072, ipb + (size_t)bx * 131072,
             lds, lds + 4096, acc);
  const int lane = threadIdx.x & 63;
  const int wave = threadIdx.x >> 6;
  const int wr = wave >> 1, wc = wave & 1;
  float inv2 = 0.5f * expf(-2.0f * ll[0]);
  float noise = expf(ln[0]);
#pragma unroll
  for (int m = 0; m < 4; m++)
#pragma unroll
    for (int j = 0; j < 4; j++) {
      const size_t grow = by * 128 + wr * 64 + m * 16 + (lane >> 4) * 4 + j;
      float rn = ni[grow];
      float part = 0.f;
#pragma unroll
      for (int n = 0; n < 4; n++) {
        const size_t gcol = bx * 128 + wc * 64 + n * 16 + (lane & 15);
        float d2 = fmaxf(rn + ni[gcol] - 2.0f * acc[m][n][j], 0.0f);
        float kv = (grow == gcol) ? (1.0f + noise) : expf(-inv2 * d2);
        kii[grow * 1024 + gcol] = f2bf(kv);
        part += fabsf(kv);
      }
      part += __shfl_xor(part, 1);
      part += __shfl_xor(part, 2);
      part += __shfl_xor(part, 4);
      part += __shfl_xor(part, 8);
      if ((lane & 15) == 0) atomicAdd(&rs[grow], part);
    }
}

// ---------- batch1 body: z=0: R2 = I-2cK+c^2*K@K ; z=1: T1 = 2W - c*W@K ----
__device__ __forceinline__ void batch1_body(int bid, u16* lds,
                                            const u16* kii, const u16* Wb,
                                            u16* R2b, u16* T1b,
                                            const float* sc) {
  const int z = bid >> 6, r = bid & 63;
  const int by = r >> 3, bx = r & 7;
  f32x4 acc[4][4] = {};
  const u16* Abase = z ? Wb : kii;
  small_core(Abase + (size_t)by * 131072, kii + (size_t)bx * 131072,
             lds, lds + 4096, acc);
  const int lane = threadIdx.x & 63;
  const int wave = threadIdx.x >> 6;
  const int wr = wave >> 1, wc = wave & 1;
  const float c = sc[0];
#pragma unroll
  for (int m = 0; m < 4; m++)
#pragma unroll
    for (int j = 0; j < 4; j++) {
      const size_t grow = by * 128 + wr * 64 + m * 16 + (lane >> 4) * 4 + j;
#pragma unroll
      for (int n = 0; n < 4; n++) {
        const size_t gcol = bx * 128 + wc * 64 + n * 16 + (lane & 15);
        const size_t o = grow * 1024 + gcol;
        float v = acc[m][n][j];
        if (z == 0) {
          float idv = (grow == gcol) ? 1.0f : 0.0f;
          R2b[o] = f2bf(idv - 2.0f * c * bf2f(kii[o]) + c * c * v);
        } else {
          T1b[o] = f2bf(2.0f * bf2f(Wb[o]) - c * v);
        }
      }
    }
}

// ---------- batch2 body: z=0: S -> U[0:1024] ; z=1: W2T -> U[1024:2048] ----
__device__ __forceinline__ void batch2_body(int z, int by, int bx, u16* lds,
                                            const u16* kii, const u16* R2b,
                                            const u16* T1b, u16* U,
                                            const float* sc) {
  f32x4 acc[4][4] = {};
  const u16* Abase = z ? T1b : kii;
  small_core(Abase + (size_t)by * 131072, R2b + (size_t)bx * 131072,
             lds, lds + 4096, acc);
  const int lane = threadIdx.x & 63;
  const int wave = threadIdx.x >> 6;
  const int wr = wave >> 1, wc = wave & 1;
  const float c = sc[0], s = sc[1];
#pragma unroll
  for (int m = 0; m < 4; m++)
#pragma unroll
    for (int j = 0; j < 4; j++) {
      const size_t grow = by * 128 + wr * 64 + m * 16 + (lane >> 4) * 4 + j;
#pragma unroll
      for (int n = 0; n < 4; n++) {
        const size_t gcol = bx * 128 + wc * 64 + n * 16 + (lane & 15);
        const size_t o = grow * 1024 + gcol;
        float v = acc[m][n][j];
        if (z == 0) {
          float idv = (grow == gcol) ? 1.0f : 0.0f;
          U[o] = f2bf(s * (1.5f * idv - 0.5f * c * bf2f(kii[o]) +
                           0.6875f * bf2f(R2b[o]) - 0.3125f * c * v));
        } else {
          U[o + 1048576] = f2bf(c * (bf2f(T1b[o]) + v));
        }
      }
    }
}

// ---------- prep_x body: x rows -> bf16 + row norms (stride 2048) ----------
__device__ __forceinline__ void prepx_body(int bid, u16* lds,
                                           const float* x, u16* xbf,
                                           float* nx) {
  float* wsum = (float*)lds;
  for (int r = bid; r < 16384; r += 2048) {
    const float4 v = ((const float4*)(x + (size_t)r * 1024))[threadIdx.x];
    float ss = v.x * v.x + v.y * v.y + v.z * v.z + v.w * v.w;
    us4 o; o.x = f2bf(v.x); o.y = f2bf(v.y); o.z = f2bf(v.z); o.w = f2bf(v.w);
    ((us4*)(xbf + (size_t)r * 1024))[threadIdx.x] = o;
#pragma unroll
    for (int s = 32; s > 0; s >>= 1) ss += __shfl_xor(ss, s);
    if ((threadIdx.x & 63) == 0) wsum[threadIdx.x >> 6] = ss;
    __syncthreads();
    if (threadIdx.x == 0) nx[r] = wsum[0] + wsum[1] + wsum[2] + wsum[3];
    __syncthreads();
  }
}

// =================== fat kernels ===================
// fat1: kii(64, first) || prep_x(2048)
__global__ __launch_bounds__(256) void fat1(
    const float* __restrict__ x, u16* __restrict__ xbf, float* __restrict__ nx,
    const u16* __restrict__ ipb, u16* __restrict__ kii,
    const float* __restrict__ ni, const float* __restrict__ ll,
    const float* __restrict__ ln, float* __restrict__ rs) {
  __shared__ u16 lds[8192];  // 16 KiB
  const int bid = blockIdx.x;
  if (bid < 64) kii_body(bid, lds, ipb, kii, ni, ll, ln, rs);
  else          prepx_body(bid - 64, lds, x, xbf, nx);
}

// fat2: batch1(128, first) || Kxi(1024)
__global__ __launch_bounds__(256, 2) void fat2(
    const u16* __restrict__ xbf, const u16* __restrict__ ipb,
    u16* __restrict__ kxib,
    const float* __restrict__ nx, const float* __restrict__ ni,
    const float* __restrict__ ll, float* __restrict__ qb,
    const u16* __restrict__ kii, const u16* __restrict__ wbf,
    u16* __restrict__ R2b, u16* __restrict__ t1b,
    const float* __restrict__ sc) {
  __shared__ u16 lds[32768];  // 64 KiB
  const int bid = blockIdx.x;
  if (bid < 128) batch1_body(bid, lds, kii, wbf, R2b, t1b, sc);
  else big_body<0>(bid - 128, lds, xbf, ipb, nullptr, nullptr, kxib,
                   nx, ni, ll, qb);
}

// batch2a: S only (z=0)
__global__ __launch_bounds__(256) void kbatch2a(
    const u16* __restrict__ kii, const u16* __restrict__ R2b,
    const u16* __restrict__ t1b, u16* __restrict__ U,
    const float* __restrict__ sc) {
  __shared__ u16 lds[8192];
  batch2_body(0, blockIdx.y, blockIdx.x, lds, kii, R2b, t1b, U, sc);
}

// fat3: batch2b{W2T}(64, first) || q(1024)
__global__ __launch_bounds__(256, 2) void fat3(
    const u16* __restrict__ kxib, const u16* __restrict__ U,
    float* __restrict__ qb,
    const u16* __restrict__ kii, const u16* __restrict__ R2b,
    const u16* __restrict__ t1b, u16* __restrict__ Uw,
    const float* __restrict__ sc) {
  __shared__ u16 lds[32768];
  const int bid = blockIdx.x;
  if (bid < 64) batch2_body(1, bid >> 3, bid & 7, lds, kii, R2b, t1b, Uw, sc);
  else big_body<2>(bid - 64, lds, kxib, U, nullptr, nullptr, nullptr,
                   nullptr, nullptr, nullptr, qb);
}

// mean pass (+ fused var from qb; dispatch boundary fences qb)
__global__ __launch_bounds__(256, 2) void kmean(
    const u16* __restrict__ kxib, const u16* __restrict__ w2t,
    float* __restrict__ meanO, float* __restrict__ varO,
    float* __restrict__ qb) {
  __shared__ u16 lds[32768];
  big_body<1>(blockIdx.x, lds, kxib, w2t, meanO, varO, nullptr,
              nullptr, nullptr, nullptr, qb);
}

// ---------- ip rows (norms) + W convert + rs zero ----------
__global__ __launch_bounds__(256) void prep_ipw(const float* __restrict__ ip,
                                                const float* __restrict__ W,
                                                u16* __restrict__ ipb,
                                                u16* __restrict__ wbf,
                                                float* __restrict__ ni,
                                                float* __restrict__ rs) {
  __shared__ float wsum[4];
  int b = blockIdx.x;
  if (b < 1024) {
    const float4 v = ((const float4*)(ip + (size_t)b * 1024))[threadIdx.x];
    float ss = v.x * v.x + v.y * v.y + v.z * v.z + v.w * v.w;
    us4 o; o.x = f2bf(v.x); o.y = f2bf(v.y); o.z = f2bf(v.z); o.w = f2bf(v.w);
    ((us4*)(ipb + (size_t)b * 1024))[threadIdx.x] = o;
#pragma unroll
    for (int s = 32; s > 0; s >>= 1) ss += __shfl_xor(ss, s);
    if ((threadIdx.x & 63) == 0) wsum[threadIdx.x >> 6] = ss;
    __syncthreads();
    if (threadIdx.x == 0) {
      ni[b] = wsum[0] + wsum[1] + wsum[2] + wsum[3];
      rs[b] = 0.0f;
    }
  } else {
    int r = b - 1024;
    const float4 v = ((const float4*)(W + (size_t)r * 1024))[threadIdx.x];
    us4 o; o.x = f2bf(v.x); o.y = f2bf(v.y); o.z = f2bf(v.z); o.w = f2bf(v.w);
    ((us4*)(wbf + (size_t)r * 1024))[threadIdx.x] = o;
  }
}

__global__ __launch_bounds__(256) void gmax_inv(const float* __restrict__ rs,
                                                float* __restrict__ sc) {
  __shared__ float wm[4];
  float m = 0.f;
  for (int i = threadIdx.x; i < 1024; i += 256) m = fmaxf(m, rs[i]);
#pragma unroll
  for (int o = 32; o > 0; o >>= 1) m = fmaxf(m, __shfl_xor(m, o));
  if ((threadIdx.x & 63) == 0) wm[threadIdx.x >> 6] = m;
  __syncthreads();
  if (threadIdx.x == 0) {
    float c = 1.0f / fmaxf(fmaxf(wm[0], wm[1]), fmaxf(wm[2], wm[3]));
    sc[0] = c;
    sc[1] = sqrtf(c);
  }
}

extern "C" void kernel_launch(void* const* d_in, const int* in_sizes, int n_in,
                              void* d_out, int out_size, void* d_ws, size_t ws_size,
                              hipStream_t stream) {
  const float* x  = (const float*)d_in[0];
  const float* ip = (const float*)d_in[1];
  const float* ll = (const float*)d_in[2];
  const float* ln = (const float*)d_in[3];
  const float* W  = (const float*)d_in[4];

  char* ws = (char*)d_ws;
  const size_t MB = 1ull << 20;
  u16* kxib = (u16*)(ws + 0 * MB);    // 32 MiB
  u16* xbf  = (u16*)(ws + 32 * MB);   // 32 MiB
  u16* ipb  = (u16*)(ws + 64 * MB);   // 2 MiB
  u16* wbf  = (u16*)(ws + 66 * MB);   // 2 MiB
  u16* kii  = (u16*)(ws + 68 * MB);   // 2 MiB
  u16* R2b  = (u16*)(ws + 70 * MB);   // 2 MiB
  u16* Ub   = (u16*)(ws + 74 * MB);   // 4 MiB  [S ; W2T]
  u16* t1b  = (u16*)(ws + 78 * MB);   // 2 MiB
  float* nx = (float*)(ws + 80 * MB);
  float* qb = (float*)(ws + 80 * MB + 128 * 1024);
  float* ni = (float*)(ws + 80 * MB + 256 * 1024);
  float* rs = (float*)(ws + 80 * MB + 512 * 1024);
  float* sc = (float*)(ws + 80 * MB + 768 * 1024);

  float* meanO = (float*)d_out;
  float* varO  = meanO + 16777216ull;

  // ip/W prep (kii's inputs) first
  prep_ipw<<<2048, 256, 0, stream>>>(ip, W, ipb, wbf, ni, rs);

  // kii (64, first) || prep_x (2048)
  fat1<<<2112, 256, 0, stream>>>(x, xbf, nx, ipb, kii, ni, ll, ln, rs);

  gmax_inv<<<1, 256, 0, stream>>>(rs, sc);

  // batch1 (128, first) || Kxi (1024); qb zeroed by Kxi blocks
  fat2<<<1152, 256, 0, stream>>>(xbf, ipb, kxib, nx, ni, ll, qb,
                                 kii, wbf, R2b, t1b, sc);

  // S -> U[0:1024]
  kbatch2a<<<dim3(8, 8), 256, 0, stream>>>(kii, R2b, t1b, Ub, sc);

  // batch2b{W2T} (64, first) || q (1024)
  fat3<<<1088, 256, 0, stream>>>(kxib, Ub, qb, kii, R2b, t1b, Ub, sc);

  // mean + fused var -> d_out
  kmean<<<1024, 256, 0, stream>>>(kxib, Ub + 1048576, meanO, varO, qb);
}

// Round 15
// 203.003 us; speedup vs baseline: 1.6882x; 1.0468x over previous
//
#include <hip/hip_runtime.h>
#include <hip/hip_bf16.h>
#include <math.h>

// SentenceGP: B=16,S=1024,D=1024,M=1024,O=1024
// out = [mean (16,1024,1024) f32][softplus(var) (16,1024,1024) f32]
//
// Pipeline (R15 = R14 minus gmax dispatch, S via pipelined big_body):
//  prep_ipw: ip->bf16 + norms | W->bf16 | rs=0
//  fat1: kii(64, first) || prep_x(2048)             [kii hidden]
//  fat2: batch1{R2,T1}(128, first) || Kxi(1024)     [batch1 hidden; zeroes qb]
//        (c = 1/max(rs) computed per-block — gmax kernel removed; max is
//         order-independent so all blocks agree bitwise)
//  gemm_s: S -> U[0:1024]   [64 blocks, big_body pipeline, EPI 3]
//  fat3: batch2b{W2T}(64, first) || q(1024)         [W2T hidden]
//  kmean: mean + fused var -> d_out                 [qb fenced by dispatch]
//
// Big-GEMM body: 128x128 tile, BK=64, 4 waves, 64 KiB LDS, 2 blocks/CU,
// XOR-swizzled LDS, counted vmcnt(4)/tile, one s_barrier/phase.

typedef unsigned short u16;
typedef __attribute__((ext_vector_type(8))) short short8;
typedef __attribute__((ext_vector_type(4))) float f32x4;
typedef __attribute__((ext_vector_type(4))) unsigned short us4;

__device__ __forceinline__ float bf2f(u16 b) {
  union { unsigned u; float f; } x; x.u = ((unsigned)b) << 16; return x.f;
}
__device__ __forceinline__ u16 f2bf(float f) {
  union { float f; unsigned u; } x; x.f = f;
  unsigned r = x.u + 0x7fffu + ((x.u >> 16) & 1u);
  return (u16)(r >> 16);
}

__device__ __forceinline__ void gl_lds16(const void* g, void* l) {
  __builtin_amdgcn_global_load_lds(
      (const __attribute__((address_space(1))) void*)g,
      (__attribute__((address_space(3))) void*)l, 16, 0, 0);
}

// c = 1/max(rs[0..1023]); bitwise-identical across blocks (max is
// order-independent). sm = 4-float LDS scratch; callers ensure LDS is dead.
__device__ __forceinline__ float local_cmax(const float* rs, float* sm) {
  float m = 0.f;
  for (int i = threadIdx.x; i < 1024; i += 256) m = fmaxf(m, rs[i]);
#pragma unroll
  for (int o = 32; o > 0; o >>= 1) m = fmaxf(m, __shfl_xor(m, o));
  __syncthreads();
  if ((threadIdx.x & 63) == 0) sm[threadIdx.x >> 6] = m;
  __syncthreads();
  return 1.0f / fmaxf(fmaxf(sm[0], sm[1]), fmaxf(sm[2], sm[3]));
}

// =================== big GEMM body: 128^2, 4 waves, 2 blocks/CU ============
// EPI 0: Kxi = bf16(exp(-inv2*max(rn+cn-2c,0))); zeroes qb.
// EPI 1: mean f32 store + fused var = softplus(1-q[row]).
// EPI 2: q[row] += sum_col acc^2 (atomic).
// EPI 3: S = s*(1.5I - c/2*Ag - 0.3125c*acc + 0.6875*Bg)  [A=kii, B=R2;
//        small 8x8 grid decode; rowN carries rs]
template <int EPI>
__device__ __forceinline__ void big_body(
    int bid, u16* lds,
    const u16* Ag, const u16* Bg,
    float* outF, float* varF, u16* outB,
    const float* rowN, const float* colN,
    const float* p_ll, float* qb) {
  constexpr int NT = 16;  // K / 64
  const int tid = threadIdx.x;
  const int lane = tid & 63;
  const int wave = tid >> 6;                  // 4 waves
  const int wr = wave >> 1, wc = wave & 1;    // 2 x 2
  const int fro = lane & 15, khi = lane >> 4;
  size_t brow, bcol;
  if (EPI == 3) {             // 64-block 8x8 grid
    brow = (size_t)(bid >> 3);
    bcol = (size_t)(bid & 7);
  } else {                    // 1024-block XCD-grouped grid
    const int xcd = bid & 7, j7 = bid >> 3;
    brow = (size_t)(xcd * 16 + (j7 >> 3));    // row-panel -> one XCD
    bcol = (size_t)(j7 & 7);
  }

  if (EPI == 0) {  // zero q accumulator for the later q pass
    if (tid < 16) qb[(size_t)bid * 16 + tid] = 0.0f;
  }

  f32x4 acc[4][4] = {};

  auto stageA = [&](int tt, int bb) {
#pragma unroll
    for (int c = 0; c < 4; ++c) {
      const int ci = tid + 256 * c;      // 1024 chunks of 8 u16
      const int row = ci >> 3;           // 0..127
      const int gk = (ci & 7) ^ (row & 7);
      gl_lds16(Ag + (size_t)(brow * 128 + row) * 1024 + tt * 64 + gk * 8,
               &lds[bb * 16384 + ci * 8]);
    }
  };
  auto stageB = [&](int tt, int bb) {
#pragma unroll
    for (int c = 0; c < 4; ++c) {
      const int ci = tid + 256 * c;
      const int row = ci >> 3;
      const int gk = (ci & 7) ^ (row & 7);
      gl_lds16(Bg + (size_t)(bcol * 128 + row) * 1024 + tt * 64 + gk * 8,
               &lds[bb * 16384 + 8192 + ci * 8]);
    }
  };

  // prologue: A(0)+B(0) -> buf0, B(1) -> buf1. vmcnt(4): tile0 landed.
  stageA(0, 0);
  stageB(0, 0);
  stageB(1, 1);
  asm volatile("s_waitcnt vmcnt(4)" ::: "memory");
  __builtin_amdgcn_s_barrier();

  for (int t = 0; t < NT; ++t) {
    const int cb = t & 1;
    const int ab = cb * 16384;
    const int bb = cb * 16384 + 8192;
    short8 bfrag[4][2];
#pragma unroll
    for (int p = 0; p < 4; ++p) {
      short8 afr[2];
      const int rr = wr * 64 + p * 16 + fro;
#pragma unroll
      for (int s = 0; s < 2; ++s) {
        const int kl = (s * 4 + khi) ^ (rr & 7);
        afr[s] = *(const short8*)&lds[ab + (rr * 8 + kl) * 8];
      }
      if (p == 0) {
#pragma unroll
        for (int n = 0; n < 4; ++n) {
          const int cc = wc * 64 + n * 16 + fro;
#pragma unroll
          for (int s = 0; s < 2; ++s) {
            const int kl = (s * 4 + khi) ^ (cc & 7);
            bfrag[n][s] = *(const short8*)&lds[bb + (cc * 8 + kl) * 8];
          }
        }
        if (t + 1 < NT) stageA(t + 1, cb ^ 1);   // A(t-1) done @ t-1 p3
      } else if (p == 1) {
        if (t + 2 < NT) stageB(t + 2, cb);        // B(t) done @ p0
      }
      __builtin_amdgcn_s_setprio(1);
#pragma unroll
      for (int n = 0; n < 4; ++n)
#pragma unroll
        for (int s = 0; s < 2; ++s)
          acc[p][n] = __builtin_amdgcn_mfma_f32_16x16x32_bf16(
              afr[s], bfrag[n][s], acc[p][n], 0, 0, 0);
      __builtin_amdgcn_s_setprio(0);
      if (p == 3) {
        if (t < NT - 2) asm volatile("s_waitcnt vmcnt(4)" ::: "memory");
        else            asm volatile("s_waitcnt vmcnt(0)" ::: "memory");
      }
      __builtin_amdgcn_s_barrier();
    }
  }

  // ---- epilogue ----
  float inv2 = 0.f, cc2 = 0.f, ss2 = 0.f;
  if (EPI == 0) inv2 = 0.5f * expf(-2.0f * p_ll[0]);
  if (EPI == 3) {
    __syncthreads();                       // K-loop LDS dead; full fence
    cc2 = local_cmax(rowN, (float*)lds);   // rowN carries rs
    ss2 = sqrtf(cc2);
  }
#pragma unroll
  for (int m = 0; m < 4; m++) {
#pragma unroll
    for (int j = 0; j < 4; j++) {
      const size_t grow = brow * 128 + wr * 64 + m * 16 + khi * 4 + j;
      float rn = 0.f, sp = 0.f;
      if (EPI == 0) rn = rowN[grow];
      if (EPI == 1) {
        float vq = 1.0f - qb[grow];  // K_xx diag == 1 exactly
        sp = fmaxf(vq, 0.f) + log1pf(expf(-fabsf(vq)));
      }
      float part = 0.f;
#pragma unroll
      for (int n = 0; n < 4; n++) {
        const size_t gcol = bcol * 128 + wc * 64 + n * 16 + fro;
        const size_t o = grow * 1024 + gcol;
        float v = acc[m][n][j];
        if (EPI == 0) {
          float d2 = fmaxf(rn + colN[gcol] - 2.0f * v, 0.0f);
          outB[o] = f2bf(expf(-inv2 * d2));
        } else if (EPI == 1) {
          outF[o] = v;
          varF[o] = sp;
        } else if (EPI == 3) {
          float idv = (grow == gcol) ? 1.0f : 0.0f;
          outB[o] = f2bf(ss2 * (1.5f * idv - 0.5f * cc2 * bf2f(Ag[o]) +
                                0.6875f * bf2f(Bg[o]) - 0.3125f * cc2 * v));
        } else {
          part += v * v;
        }
      }
      if (EPI == 2) {
        part += __shfl_xor(part, 1);
        part += __shfl_xor(part, 2);
        part += __shfl_xor(part, 4);
        part += __shfl_xor(part, 8);
        if (fro == 0) atomicAdd(&qb[grow], part);
      }
    }
  }
}

// =================== small 128^2 GEMM core (K=1024, B^T layout) ===========
__device__ __forceinline__ void small_core(const u16* Ap, const u16* Bp,
                                           u16* As, u16* Bs,
                                           f32x4 (&acc)[4][4]) {
  const int tid = threadIdx.x;
  const int lane = tid & 63;
  const int wave = tid >> 6;
  const int wr = wave >> 1, wc = wave & 1;
  const int idx0 = tid, idx1 = tid + 256;
  const u16* gA0 = Ap + (size_t)(idx0 >> 2) * 1024 + (size_t)(idx0 & 3) * 8;
  const u16* gA1 = Ap + (size_t)(idx1 >> 2) * 1024 + (size_t)(idx1 & 3) * 8;
  const u16* gB0 = Bp + (size_t)(idx0 >> 2) * 1024 + (size_t)(idx0 & 3) * 8;
  const u16* gB1 = Bp + (size_t)(idx1 >> 2) * 1024 + (size_t)(idx1 & 3) * 8;
  u16* lA0 = &As[idx0 * 8]; u16* lA1 = &As[idx1 * 8];
  u16* lB0 = &Bs[idx0 * 8]; u16* lB1 = &Bs[idx1 * 8];
  const int fro = lane & 15;
  const int ko = (lane >> 4) * 8;

  for (int kt = 0; kt < 1024; kt += 32) {
    gl_lds16(gA0 + kt, lA0);
    gl_lds16(gA1 + kt, lA1);
    gl_lds16(gB0 + kt, lB0);
    gl_lds16(gB1 + kt, lB1);
    __syncthreads();
    short8 af[4], bfr[4];
#pragma unroll
    for (int m = 0; m < 4; m++) {
      af[m]  = *(const short8*)&As[(wr * 64 + m * 16 + fro) * 32 + ko];
      bfr[m] = *(const short8*)&Bs[(wc * 64 + m * 16 + fro) * 32 + ko];
    }
#pragma unroll
    for (int m = 0; m < 4; m++)
#pragma unroll
      for (int n = 0; n < 4; n++)
        acc[m][n] = __builtin_amdgcn_mfma_f32_16x16x32_bf16(af[m], bfr[n], acc[m][n], 0, 0, 0);
    __syncthreads();
  }
}

// ---------- kii body: rbf(ip,ip), diag=1+noise, fused Gershgorin ----------
__device__ __forceinline__ void kii_body(int bid, u16* lds,
                                         const u16* ipb, u16* kii,
                                         const float* ni, const float* ll,
                                         const float* ln, float* rs) {
  const int by = bid >> 3, bx = bid & 7;
  f32x4 acc[4][4] = {};
  small_core(ipb + (size_t)by * 131072, ipb + (size_t)bx * 131072,
             lds, lds + 4096, acc);
  const int lane = threadIdx.x & 63;
  const int wave = threadIdx.x >> 6;
  const int wr = wave >> 1, wc = wave & 1;
  float inv2 = 0.5f * expf(-2.0f * ll[0]);
  float noise = expf(ln[0]);
#pragma unroll
  for (int m = 0; m < 4; m++)
#pragma unroll
    for (int j = 0; j < 4; j++) {
      const size_t grow = by * 128 + wr * 64 + m * 16 + (lane >> 4) * 4 + j;
      float rn = ni[grow];
      float part = 0.f;
#pragma unroll
      for (int n = 0; n < 4; n++) {
        const size_t gcol = bx * 128 + wc * 64 + n * 16 + (lane & 15);
        float d2 = fmaxf(rn + ni[gcol] - 2.0f * acc[m][n][j], 0.0f);
        float kv = (grow == gcol) ? (1.0f + noise) : expf(-inv2 * d2);
        kii[grow * 1024 + gcol] = f2bf(kv);
        part += fabsf(kv);
      }
      part += __shfl_xor(part, 1);
      part += __shfl_xor(part, 2);
      part += __shfl_xor(part, 4);
      part += __shfl_xor(part, 8);
      if ((lane & 15) == 0) atomicAdd(&rs[grow], part);
    }
}

// ---------- batch1 body: z=0: R2 = I-2cK+c^2*K@K ; z=1: T1 = 2W - c*W@K ----
__device__ __forceinline__ void batch1_body(int bid, u16* lds,
                                            const u16* kii, const u16* Wb,
                                            u16* R2b, u16* T1b,
                                            const float* rs) {
  const int z = bid >> 6, r = bid & 63;
  const int by = r >> 3, bx = r & 7;
  f32x4 acc[4][4] = {};
  const u16* Abase = z ? Wb : kii;
  small_core(Abase + (size_t)by * 131072, kii + (size_t)bx * 131072,
             lds, lds + 4096, acc);
  __syncthreads();
  const float c = local_cmax(rs, (float*)lds);
  const int lane = threadIdx.x & 63;
  const int wave = threadIdx.x >> 6;
  const int wr = wave >> 1, wc = wave & 1;
#pragma unroll
  for (int m = 0; m < 4; m++)
#pragma unroll
    for (int j = 0; j < 4; j++) {
      const size_t grow = by * 128 + wr * 64 + m * 16 + (lane >> 4) * 4 + j;
#pragma unroll
      for (int n = 0; n < 4; n++) {
        const size_t gcol = bx * 128 + wc * 64 + n * 16 + (lane & 15);
        const size_t o = grow * 1024 + gcol;
        float v = acc[m][n][j];
        if (z == 0) {
          float idv = (grow == gcol) ? 1.0f : 0.0f;
          R2b[o] = f2bf(idv - 2.0f * c * bf2f(kii[o]) + c * c * v);
        } else {
          T1b[o] = f2bf(2.0f * bf2f(Wb[o]) - c * v);
        }
      }
    }
}

// ---------- batch2b body: W2T = c*(T1 + T1@R2) -> U[1024:2048] ----------
__device__ __forceinline__ void batch2b_body(int by, int bx, u16* lds,
                                             const u16* R2b, const u16* T1b,
                                             u16* U, const float* rs) {
  f32x4 acc[4][4] = {};
  small_core(T1b + (size_t)by * 131072, R2b + (size_t)bx * 131072,
             lds, lds + 4096, acc);
  __syncthreads();
  const float c = local_cmax(rs, (float*)lds);
  const int lane = threadIdx.x & 63;
  const int wave = threadIdx.x >> 6;
  const int wr = wave >> 1, wc = wave & 1;
#pragma unroll
  for (int m = 0; m < 4; m++)
#pragma unroll
    for (int j = 0; j < 4; j++) {
      const size_t grow = by * 128 + wr * 64 + m * 16 + (lane >> 4) * 4 + j;
#pragma unroll
      for (int n = 0; n < 4; n++) {
        const size_t gcol = bx * 128 + wc * 64 + n * 16 + (lane & 15);
        const size_t o = grow * 1024 + gcol;
        U[o + 1048576] = f2bf(c * (bf2f(T1b[o]) + acc[m][n][j]));
      }
    }
}

// ---------- prep_x body: x rows -> bf16 + row norms (stride 2048) ----------
__device__ __forceinline__ void prepx_body(int bid, u16* lds,
                                           const float* x, u16* xbf,
                                           float* nx) {
  float* wsum = (float*)lds;
  for (int r = bid; r < 16384; r += 2048) {
    const float4 v = ((const float4*)(x + (size_t)r * 1024))[threadIdx.x];
    float ss = v.x * v.x + v.y * v.y + v.z * v.z + v.w * v.w;
    us4 o; o.x = f2bf(v.x); o.y = f2bf(v.y); o.z = f2bf(v.z); o.w = f2bf(v.w);
    ((us4*)(xbf + (size_t)r * 1024))[threadIdx.x] = o;
#pragma unroll
    for (int s = 32; s > 0; s >>= 1) ss += __shfl_xor(ss, s);
    if ((threadIdx.x & 63) == 0) wsum[threadIdx.x >> 6] = ss;
    __syncthreads();
    if (threadIdx.x == 0) nx[r] = wsum[0] + wsum[1] + wsum[2] + wsum[3];
    __syncthreads();
  }
}

// =================== fat kernels ===================
// fat1: kii(64, first) || prep_x(2048)
__global__ __launch_bounds__(256) void fat1(
    const float* __restrict__ x, u16* __restrict__ xbf, float* __restrict__ nx,
    const u16* __restrict__ ipb, u16* __restrict__ kii,
    const float* __restrict__ ni, const float* __restrict__ ll,
    const float* __restrict__ ln, float* __restrict__ rs) {
  __shared__ u16 lds[8192];  // 16 KiB
  const int bid = blockIdx.x;
  if (bid < 64) kii_body(bid, lds, ipb, kii, ni, ll, ln, rs);
  else          prepx_body(bid - 64, lds, x, xbf, nx);
}

// fat2: batch1(128, first) || Kxi(1024)
__global__ __launch_bounds__(256, 2) void fat2(
    const u16* __restrict__ xbf, const u16* __restrict__ ipb,
    u16* __restrict__ kxib,
    const float* __restrict__ nx, const float* __restrict__ ni,
    const float* __restrict__ ll, float* __restrict__ qb,
    const u16* __restrict__ kii, const u16* __restrict__ wbf,
    u16* __restrict__ R2b, u16* __restrict__ t1b,
    const float* __restrict__ rs) {
  __shared__ u16 lds[32768];  // 64 KiB
  const int bid = blockIdx.x;
  if (bid < 128) batch1_body(bid, lds, kii, wbf, R2b, t1b, rs);
  else big_body<0>(bid - 128, lds, xbf, ipb, nullptr, nullptr, kxib,
                   nx, ni, ll, qb);
}

// gemm_s: S -> U[0:1024] via big_body pipeline (64 blocks)
__global__ __launch_bounds__(256, 2) void gemm_s(
    const u16* __restrict__ kii, const u16* __restrict__ R2b,
    u16* __restrict__ U, const float* __restrict__ rs) {
  __shared__ u16 lds[32768];
  big_body<3>(blockIdx.x, lds, kii, R2b, nullptr, nullptr, U,
              rs, nullptr, nullptr, nullptr);
}

// fat3: batch2b{W2T}(64, first) || q(1024)
__global__ __launch_bounds__(256, 2) void fat3(
    const u16* __restrict__ kxib, const u16* __restrict__ U,
    float* __restrict__ qb,
    const u16* __restrict__ R2b, const u16* __restrict__ t1b,
    u16* __restrict__ Uw, const float* __restrict__ rs) {
  __shared__ u16 lds[32768];
  const int bid = blockIdx.x;
  if (bid < 64) batch2b_body(bid >> 3, bid & 7, lds, R2b, t1b, Uw, rs);
  else big_body<2>(bid - 64, lds, kxib, U, nullptr, nullptr, nullptr,
                   nullptr, nullptr, nullptr, qb);
}

// mean pass (+ fused var from qb; dispatch boundary fences qb)
__global__ __launch_bounds__(256, 2) void kmean(
    const u16* __restrict__ kxib, const u16* __restrict__ w2t,
    float* __restrict__ meanO, float* __restrict__ varO,
    float* __restrict__ qb) {
  __shared__ u16 lds[32768];
  big_body<1>(blockIdx.x, lds, kxib, w2t, meanO, varO, nullptr,
              nullptr, nullptr, nullptr, qb);
}

// ---------- ip rows (norms) + W convert + rs zero ----------
__global__ __launch_bounds__(256) void prep_ipw(const float* __restrict__ ip,
                                                const float* __restrict__ W,
                                                u16* __restrict__ ipb,
                                                u16* __restrict__ wbf,
                                                float* __restrict__ ni,
                                                float* __restrict__ rs) {
  __shared__ float wsum[4];
  int b = blockIdx.x;
  if (b < 1024) {
    const float4 v = ((const float4*)(ip + (size_t)b * 1024))[threadIdx.x];
    float ss = v.x * v.x + v.y * v.y + v.z * v.z + v.w * v.w;
    us4 o; o.x = f2bf(v.x); o.y = f2bf(v.y); o.z = f2bf(v.z); o.w = f2bf(v.w);
    ((us4*)(ipb + (size_t)b * 1024))[threadIdx.x] = o;
#pragma unroll
    for (int s = 32; s > 0; s >>= 1) ss += __shfl_xor(ss, s);
    if ((threadIdx.x & 63) == 0) wsum[threadIdx.x >> 6] = ss;
    __syncthreads();
    if (threadIdx.x == 0) {
      ni[b] = wsum[0] + wsum[1] + wsum[2] + wsum[3];
      rs[b] = 0.0f;
    }
  } else {
    int r = b - 1024;
    const float4 v = ((const float4*)(W + (size_t)r * 1024))[threadIdx.x];
    us4 o; o.x = f2bf(v.x); o.y = f2bf(v.y); o.z = f2bf(v.z); o.w = f2bf(v.w);
    ((us4*)(wbf + (size_t)r * 1024))[threadIdx.x] = o;
  }
}

extern "C" void kernel_launch(void* const* d_in, const int* in_sizes, int n_in,
                              void* d_out, int out_size, void* d_ws, size_t ws_size,
                              hipStream_t stream) {
  const float* x  = (const float*)d_in[0];
  const float* ip = (const float*)d_in[1];
  const float* ll = (const float*)d_in[2];
  const float* ln = (const float*)d_in[3];
  const float* W  = (const float*)d_in[4];

  char* ws = (char*)d_ws;
  const size_t MB = 1ull << 20;
  u16* kxib = (u16*)(ws + 0 * MB);    // 32 MiB
  u16* xbf  = (u16*)(ws + 32 * MB);   // 32 MiB
  u16* ipb  = (u16*)(ws + 64 * MB);   // 2 MiB
  u16* wbf  = (u16*)(ws + 66 * MB);   // 2 MiB
  u16* kii  = (u16*)(ws + 68 * MB);   // 2 MiB
  u16* R2b  = (u16*)(ws + 70 * MB);   // 2 MiB
  u16* Ub   = (u16*)(ws + 74 * MB);   // 4 MiB  [S ; W2T]
  u16* t1b  = (u16*)(ws + 78 * MB);   // 2 MiB
  float* nx = (float*)(ws + 80 * MB);
  float* qb = (float*)(ws + 80 * MB + 128 * 1024);
  float* ni = (float*)(ws + 80 * MB + 256 * 1024);
  float* rs = (float*)(ws + 80 * MB + 512 * 1024);

  float* meanO = (float*)d_out;
  float* varO  = meanO + 16777216ull;

  // ip/W prep (kii's inputs) first
  prep_ipw<<<2048, 256, 0, stream>>>(ip, W, ipb, wbf, ni, rs);

  // kii (64, first) || prep_x (2048)
  fat1<<<2112, 256, 0, stream>>>(x, xbf, nx, ipb, kii, ni, ll, ln, rs);

  // batch1 (128, first) || Kxi (1024); qb zeroed by Kxi blocks
  fat2<<<1152, 256, 0, stream>>>(xbf, ipb, kxib, nx, ni, ll, qb,
                                 kii, wbf, R2b, t1b, rs);

  // S -> U[0:1024]  (pipelined, 64 blocks)
  gemm_s<<<64, 256, 0, stream>>>(kii, R2b, Ub, rs);

  // batch2b{W2T} (64, first) || q (1024)
  fat3<<<1088, 256, 0, stream>>>(kxib, Ub, qb, R2b, t1b, Ub, rs);

  // mean + fused var -> d_out
  kmean<<<1024, 256, 0, stream>>>(kxib, Ub + 1048576, meanO, varO, qb);
}